// Round 7
// baseline (814.090 us; speedup 1.0000x reference)
//
#include <hip/hip_runtime.h>

#define HID 128
#define NNODES 50000
#define NEDGES 800000

typedef __attribute__((ext_vector_type(8))) short short8;
typedef __attribute__((ext_vector_type(4))) float f32x4;

union U8 { short8 v; unsigned short u[8]; };

__device__ __forceinline__ unsigned short f2b(float f) {
  unsigned int u = __float_as_uint(f);
  u += 0x7FFFu + ((u >> 16) & 1u);
  return (unsigned short)(u >> 16);
}

// packed RNE f32->bf16x2 (lo = a, hi = b) — plain C.
// (inline-asm v_cvt_pk_bf16_f32 was proven WRONG on this target in r4 — do not reintroduce)
__device__ __forceinline__ unsigned int pk2(float a, float b) {
  unsigned int ua = __float_as_uint(a);
  ua += 0x7FFFu + ((ua >> 16) & 1u);
  unsigned int ub = __float_as_uint(b);
  ub += 0x7FFFu + ((ub >> 16) & 1u);
  return (ua >> 16) | (ub & 0xFFFF0000u);
}

// cheap round-half-up pack (tie behavior differs from RNE only; 5 VALU, perm-fusable)
__device__ __forceinline__ unsigned int pk2h(float a, float b) {
  unsigned int ua = __float_as_uint(a) + 0x8000u;
  unsigned int ub = __float_as_uint(b) + 0x8000u;
  return (ua >> 16) | (ub & 0xFFFF0000u);
}

// packed bf16 atomic add: mem[addr] += lo, mem[addr+2] += hi  (gfx950 ISA; verified r3)
__device__ __forceinline__ void atomicPkAddBf16(unsigned short* addr, unsigned int packed) {
  asm volatile("global_atomic_pk_add_bf16 %0, %1, off" :: "v"(addr), "v"(packed) : "memory");
}

// ---- pack weights into bf16 fragment-native layout ----
// ws elem[((k>>3)*128 + col)*8 + (k&7)] = bf16(w[k*128 + col])
// segments (bf16 elems): W1p [0,36864) K=288(src 280), W2p [36864,53248) K=128,
// XW1p [53248,69632) K=128, NW1p [69632,102400) K=256, NW2p [102400,118784) K=128
__global__ __launch_bounds__(256) void pack_kernel(
    const float* __restrict__ ew1, const float* __restrict__ ew2,
    const float* __restrict__ xw1, const float* __restrict__ nw1,
    const float* __restrict__ nw2, unsigned short* __restrict__ ws) {
  int i = blockIdx.x * 256 + threadIdx.x;
  const float* w; int base, ksrc;
  if (i < 36864)       { w = ew1; base = 0;      ksrc = 280; }
  else if (i < 53248)  { w = ew2; base = 36864;  ksrc = 128; }
  else if (i < 69632)  { w = xw1; base = 53248;  ksrc = 128; }
  else if (i < 102400) { w = nw1; base = 69632;  ksrc = 256; }
  else if (i < 118784) { w = nw2; base = 102400; ksrc = 128; }
  else return;
  int li = i - base;
  int j = li & 7, t = li >> 3;
  int col = t & 127, kg = t >> 7;
  int k = kg * 8 + j;
  float v = (k < ksrc) ? w[k * 128 + col] : 0.0f;
  ws[i] = f2b(v);
}

// ---- pre-convert h (f32 [NNODES][128]) to bf16 copy hB ----
__global__ __launch_bounds__(256) void hpack_kernel(
    const float* __restrict__ h, unsigned short* __restrict__ hB) {
  int i = blockIdx.x * 256 + threadIdx.x;  // handles 8 elements
  const float4* p = reinterpret_cast<const float4*>(h + (size_t)i * 8);
  float4 a = p[0], b = p[1];
  uint4 u;
  u.x = pk2(a.x, a.y); u.y = pk2(a.z, a.w);
  u.z = pk2(b.x, b.y); u.w = pk2(b.z, b.w);
  *reinterpret_cast<uint4*>(hB + (size_t)i * 8) = u;
}

// ---- edge kernel: 64 edges/block, N-split waves, SWAPPED-OPERAND MFMA ----
// mfma(A=weight_frag, B=cat_frag): D[wcol][edge]; lane holds edge=lane&15,
// wcols = wavecol + j*16 + (lane>>4)*4 + {0..3}. Epilogues need no shfl pairing.
// cat tile [64][288] bf16 in LDS, row stride 576 B; zone A chunks 0..31 swizzled
// c^(row&7); zone B 32..35 swizzled 32+((c&3)^(row&3)). After GEMM1: y1 chunks
// 0..15, mij chunks 16..31.
template<int MODE>
__global__ __launch_bounds__(256, 4) void edge_kernel(
    const int* __restrict__ src, const int* __restrict__ dst,
    const float* __restrict__ ef, const float* __restrict__ h,
    const float* __restrict__ x,
    const float* __restrict__ eb1, const float* __restrict__ eb2,
    const float* __restrict__ infw, const float* __restrict__ infb,
    const float* __restrict__ xb1, const float* __restrict__ xw2,
    const float* __restrict__ xb2,
    const short8* __restrict__ W1p, const short8* __restrict__ W2p,
    const short8* __restrict__ XW1p,
    const unsigned short* __restrict__ hB,
    float* __restrict__ miF, unsigned short* __restrict__ miB,
    float* __restrict__ dx) {
  __shared__ __align__(16) char catB[64 * 576];
  __shared__ int dL[64], sL[64];
  __shared__ float relL[64][3];
  __shared__ float ppart[4][64];   // reused as qpart after sync2
  __shared__ float eijL[64];

  const int tid = threadIdx.x;
  const int e0 = blockIdx.x * 64;
  const int lane = tid & 63, w = tid >> 6;
  const int lr = lane & 15, lg = lane >> 4;
  const int l7 = lr & 7, l3 = lr & 3;
  const int colb = w*32 + lr;      // weight-frag col (A-operand row index)

  // phase 0 (distributed, 4 threads/edge): meta + edge_feat + gaussians + pad
  {
    int row = tid >> 2, sub = tid & 3;
    int e = e0 + row;
    int s = src[e], d = dst[e];
    if (sub == 0) { sL[row] = s; dL[row] = d; }
    float rx = x[3*d+0] - x[3*s+0];
    float ry = x[3*d+1] - x[3*s+1];
    float rz = x[3*d+2] - x[3*s+2];
    if (sub == 1) { relL[row][0] = rx; relL[row][1] = ry; relL[row][2] = rz; }
    float r = rx*rx + ry*ry + rz*rz;
    const float step = 100.0f / 19.0f;
    const float co = -0.5f / (step * step);
    float v6[6];
    if (sub == 0) {
      const float4 efv = reinterpret_cast<const float4*>(ef)[e];
      v6[0]=efv.x; v6[1]=efv.y; v6[2]=efv.z; v6[3]=efv.w;
      float t1 = r - step;
      v6[4] = __expf(co * r * r);
      v6[5] = __expf(co * t1 * t1);
    } else {
      #pragma unroll
      for (int q = 0; q < 6; ++q) {
        float g = (float)(sub*6 - 4 + q) * step;
        float t = r - g;
        v6[q] = __expf(co * t * t);
      }
    }
    #pragma unroll
    for (int q = 0; q < 3; ++q) {
      int c = sub*6 + q*2;
      int chunk = (c>>3) ^ (row&7);
      *reinterpret_cast<unsigned int*>(catB + row*576 + (chunk<<4) + ((c&7)<<1)) = pk2h(v6[q*2], v6[q*2+1]);
    }
    if (sub == 3) {
      U8 z;
      #pragma unroll
      for (int j = 0; j < 8; ++j) z.u[j] = 0;
      *reinterpret_cast<short8*>(catB + row*576 + ((32 + (3 ^ (row&3)))<<4)) = z.v;
    }
  }

  // gather h[dst] (chunks 3..18) and h[src] (chunks 19..34)
  #pragma unroll
  for (int it = 0; it < 8; ++it) {
    int i = tid + it*256;
    int row = i >> 5, c = i & 31;
    int node = (c < 16) ? dst[e0+row] : src[e0+row];
    int chunk = 3 + c;
    int sw = (chunk < 32) ? (chunk ^ (row&7)) : (32 + ((chunk&3) ^ (row&3)));
    if (MODE == 2) {
      short8 u = *reinterpret_cast<const short8*>(hB + (size_t)node*128 + (c&15)*8);
      *reinterpret_cast<short8*>(catB + row*576 + (sw<<4)) = u;
    } else {
      const float4* hp = reinterpret_cast<const float4*>(h + (size_t)node*128 + (c&15)*8);
      float4 a = hp[0], b = hp[1];
      uint4 u;
      u.x = pk2(a.x, a.y); u.y = pk2(a.z, a.w);
      u.z = pk2(b.x, b.y); u.w = pk2(b.z, b.w);
      *reinterpret_cast<uint4*>(catB + row*576 + (sw<<4)) = u;
    }
  }

  // prefetch GEMM1 weight fragments for kt=0,1
  short8 p00 = W1p[(0*4+lg)*128 + colb], p01 = W1p[(0*4+lg)*128 + colb + 16];
  short8 p10 = W1p[(1*4+lg)*128 + colb], p11 = W1p[(1*4+lg)*128 + colb + 16];
  __syncthreads();

  // ---- GEMM1: y1 = relu(cat @ W1 + eb1), K=288 (swapped: D[wcol][edge]) ----
  f32x4 acc[4][2];
  #pragma unroll
  for (int t = 0; t < 4; ++t) { acc[t][0] = (f32x4)0.0f; acc[t][1] = (f32x4)0.0f; }
  #pragma unroll
  for (int kt = 0; kt < 9; ++kt) {
    int ch = (kt < 8) ? ((kt*4+lg) ^ l7) : (32 + (lg ^ l3));
    short8 a0 = *reinterpret_cast<const short8*>(catB + (0*16+lr)*576 + (ch<<4));
    short8 a1 = *reinterpret_cast<const short8*>(catB + (1*16+lr)*576 + (ch<<4));
    short8 a2 = *reinterpret_cast<const short8*>(catB + (2*16+lr)*576 + (ch<<4));
    short8 a3 = *reinterpret_cast<const short8*>(catB + (3*16+lr)*576 + (ch<<4));
    short8 b0, b1;
    if (kt == 0)      { b0 = p00; b1 = p01; }
    else if (kt == 1) { b0 = p10; b1 = p11; }
    else              { b0 = W1p[(kt*4+lg)*128 + colb]; b1 = W1p[(kt*4+lg)*128 + colb + 16]; }
    acc[0][0] = __builtin_amdgcn_mfma_f32_16x16x32_bf16(b0, a0, acc[0][0], 0, 0, 0);
    acc[0][1] = __builtin_amdgcn_mfma_f32_16x16x32_bf16(b1, a0, acc[0][1], 0, 0, 0);
    acc[1][0] = __builtin_amdgcn_mfma_f32_16x16x32_bf16(b0, a1, acc[1][0], 0, 0, 0);
    acc[1][1] = __builtin_amdgcn_mfma_f32_16x16x32_bf16(b1, a1, acc[1][1], 0, 0, 0);
    acc[2][0] = __builtin_amdgcn_mfma_f32_16x16x32_bf16(b0, a2, acc[2][0], 0, 0, 0);
    acc[2][1] = __builtin_amdgcn_mfma_f32_16x16x32_bf16(b1, a2, acc[2][1], 0, 0, 0);
    acc[3][0] = __builtin_amdgcn_mfma_f32_16x16x32_bf16(b0, a3, acc[3][0], 0, 0, 0);
    acc[3][1] = __builtin_amdgcn_mfma_f32_16x16x32_bf16(b1, a3, acc[3][1], 0, 0, 0);
  }
  __syncthreads();  // all cat reads complete before y1 overwrites zone A

  // y1 epilogue: lane holds edge t*16+lr, cols c0j = w*32+j*16+lg*4+{0..3} -> one b64/tile
  {
    const int c00 = w*32 + lg*4, c01 = c00 + 16;
    float4 be0 = *reinterpret_cast<const float4*>(eb1 + c00);
    float4 be1 = *reinterpret_cast<const float4*>(eb1 + c01);
    #pragma unroll
    for (int t = 0; t < 4; ++t) {
      int row = t*16 + lr;
      char* rowB = catB + row*576;
      #pragma unroll
      for (int j = 0; j < 2; ++j) {
        const float4 be = j ? be1 : be0;
        int c0 = j ? c01 : c00;
        float v0 = fmaxf(acc[t][j][0] + be.x, 0.f);
        float v1 = fmaxf(acc[t][j][1] + be.y, 0.f);
        float v2 = fmaxf(acc[t][j][2] + be.z, 0.f);
        float v3 = fmaxf(acc[t][j][3] + be.w, 0.f);
        uint2 pv; pv.x = pk2h(v0, v1); pv.y = pk2h(v2, v3);
        int chunk = (c0>>3) ^ (row&7);
        *reinterpret_cast<uint2*>(rowB + (chunk<<4) + ((c0&7)<<1)) = pv;
      }
    }
  }
  __syncthreads();  // y1 visible to all waves

  // ---- GEMM2: mij = relu(y1 @ W2 + eb2), K=128 ----
  f32x4 acc2[4][2];
  #pragma unroll
  for (int t = 0; t < 4; ++t) { acc2[t][0] = (f32x4)0.0f; acc2[t][1] = (f32x4)0.0f; }
  #pragma unroll
  for (int kt = 0; kt < 4; ++kt) {
    int ch = (kt*4+lg) ^ l7;
    short8 a0 = *reinterpret_cast<const short8*>(catB + (0*16+lr)*576 + (ch<<4));
    short8 a1 = *reinterpret_cast<const short8*>(catB + (1*16+lr)*576 + (ch<<4));
    short8 a2 = *reinterpret_cast<const short8*>(catB + (2*16+lr)*576 + (ch<<4));
    short8 a3 = *reinterpret_cast<const short8*>(catB + (3*16+lr)*576 + (ch<<4));
    short8 b0 = W2p[(kt*4+lg)*128 + colb];
    short8 b1 = W2p[(kt*4+lg)*128 + colb + 16];
    acc2[0][0] = __builtin_amdgcn_mfma_f32_16x16x32_bf16(b0, a0, acc2[0][0], 0, 0, 0);
    acc2[0][1] = __builtin_amdgcn_mfma_f32_16x16x32_bf16(b1, a0, acc2[0][1], 0, 0, 0);
    acc2[1][0] = __builtin_amdgcn_mfma_f32_16x16x32_bf16(b0, a1, acc2[1][0], 0, 0, 0);
    acc2[1][1] = __builtin_amdgcn_mfma_f32_16x16x32_bf16(b1, a1, acc2[1][1], 0, 0, 0);
    acc2[2][0] = __builtin_amdgcn_mfma_f32_16x16x32_bf16(b0, a2, acc2[2][0], 0, 0, 0);
    acc2[2][1] = __builtin_amdgcn_mfma_f32_16x16x32_bf16(b1, a2, acc2[2][1], 0, 0, 0);
    acc2[3][0] = __builtin_amdgcn_mfma_f32_16x16x32_bf16(b0, a3, acc2[3][0], 0, 0, 0);
    acc2[3][1] = __builtin_amdgcn_mfma_f32_16x16x32_bf16(b1, a3, acc2[3][1], 0, 0, 0);
  }
  // epilogue: mval kept in acc2; mij -> chunks 16..31 (b64); per-edge inf partials
  float pl[4];
  {
    const int c00 = w*32 + lg*4, c01 = c00 + 16;
    float4 be0 = *reinterpret_cast<const float4*>(eb2 + c00);
    float4 be1 = *reinterpret_cast<const float4*>(eb2 + c01);
    float4 iw0 = *reinterpret_cast<const float4*>(infw + c00);
    float4 iw1 = *reinterpret_cast<const float4*>(infw + c01);
    #pragma unroll
    for (int t = 0; t < 4; ++t) {
      int row = t*16 + lr;
      char* rowB = catB + row*576;
      pl[t] = 0.f;
      #pragma unroll
      for (int j = 0; j < 2; ++j) {
        const float4 be = j ? be1 : be0;
        const float4 iw = j ? iw1 : iw0;
        int c0 = j ? c01 : c00;
        float v0 = fmaxf(acc2[t][j][0] + be.x, 0.f);
        float v1 = fmaxf(acc2[t][j][1] + be.y, 0.f);
        float v2 = fmaxf(acc2[t][j][2] + be.z, 0.f);
        float v3 = fmaxf(acc2[t][j][3] + be.w, 0.f);
        acc2[t][j][0] = v0; acc2[t][j][1] = v1; acc2[t][j][2] = v2; acc2[t][j][3] = v3;
        pl[t] += v0*iw.x + v1*iw.y + v2*iw.z + v3*iw.w;
        uint2 pv; pv.x = pk2h(v0, v1); pv.y = pk2h(v2, v3);
        int chunk = 16 + ((c0>>3) ^ (row&7));
        *reinterpret_cast<uint2*>(rowB + (chunk<<4) + ((c0&7)<<1)) = pv;
      }
    }
    #pragma unroll
    for (int t = 0; t < 4; ++t) {
      pl[t] += __shfl_xor(pl[t], 16, 64);
      pl[t] += __shfl_xor(pl[t], 32, 64);
    }
    if (lane < 16) {
      #pragma unroll
      for (int t = 0; t < 4; ++t) ppart[w][t*16 + lane] = pl[t];
    }
  }
  __syncthreads();  // sync1: mij + ppart ready

  if (lane < 16) {
    int row2 = w*16 + lane;
    float s2 = ppart[0][row2] + ppart[1][row2] + ppart[2][row2] + ppart[3][row2] + infb[0];
    eijL[row2] = 1.f / (1.f + __expf(-s2));
  }
  __syncthreads();  // sync2: eijL ready

  // ---- scatter mi[dst] += mij * eij (lane's 8 cols share one dst) ----
  {
    const int c00 = w*32 + lg*4, c01 = c00 + 16;
    #pragma unroll
    for (int t = 0; t < 4; ++t) {
      int row = t*16 + lr;
      int d = dL[row];
      float e = eijL[row];
      if (MODE >= 1) {
        unsigned short* bp = miB + (size_t)d*128;
        #pragma unroll
        for (int j = 0; j < 2; ++j) {
          int c0 = j ? c01 : c00;
          atomicPkAddBf16(bp + c0,     pk2h(acc2[t][j][0]*e, acc2[t][j][1]*e));
          atomicPkAddBf16(bp + c0 + 2, pk2h(acc2[t][j][2]*e, acc2[t][j][3]*e));
        }
      } else {
        float* fp = miF + (size_t)d*128;
        #pragma unroll
        for (int j = 0; j < 2; ++j) {
          int c0 = j ? c01 : c00;
          #pragma unroll
          for (int rg = 0; rg < 4; ++rg) atomicAdd(fp + c0 + rg, acc2[t][j][rg]*e);
        }
      }
    }
  }

  // ---- GEMM3: y2 = relu(mij @ XW1 + xb1); x_scale = y2 . xw2 + xb2 ----
  f32x4 acc3[4][2];
  #pragma unroll
  for (int t = 0; t < 4; ++t) { acc3[t][0] = (f32x4)0.0f; acc3[t][1] = (f32x4)0.0f; }
  #pragma unroll
  for (int kt = 0; kt < 4; ++kt) {
    int ch = 16 + ((kt*4+lg) ^ l7);
    short8 a0 = *reinterpret_cast<const short8*>(catB + (0*16+lr)*576 + (ch<<4));
    short8 a1 = *reinterpret_cast<const short8*>(catB + (1*16+lr)*576 + (ch<<4));
    short8 a2 = *reinterpret_cast<const short8*>(catB + (2*16+lr)*576 + (ch<<4));
    short8 a3 = *reinterpret_cast<const short8*>(catB + (3*16+lr)*576 + (ch<<4));
    short8 b0 = XW1p[(kt*4+lg)*128 + colb];
    short8 b1 = XW1p[(kt*4+lg)*128 + colb + 16];
    acc3[0][0] = __builtin_amdgcn_mfma_f32_16x16x32_bf16(b0, a0, acc3[0][0], 0, 0, 0);
    acc3[0][1] = __builtin_amdgcn_mfma_f32_16x16x32_bf16(b1, a0, acc3[0][1], 0, 0, 0);
    acc3[1][0] = __builtin_amdgcn_mfma_f32_16x16x32_bf16(b0, a1, acc3[1][0], 0, 0, 0);
    acc3[1][1] = __builtin_amdgcn_mfma_f32_16x16x32_bf16(b1, a1, acc3[1][1], 0, 0, 0);
    acc3[2][0] = __builtin_amdgcn_mfma_f32_16x16x32_bf16(b0, a2, acc3[2][0], 0, 0, 0);
    acc3[2][1] = __builtin_amdgcn_mfma_f32_16x16x32_bf16(b1, a2, acc3[2][1], 0, 0, 0);
    acc3[3][0] = __builtin_amdgcn_mfma_f32_16x16x32_bf16(b0, a3, acc3[3][0], 0, 0, 0);
    acc3[3][1] = __builtin_amdgcn_mfma_f32_16x16x32_bf16(b1, a3, acc3[3][1], 0, 0, 0);
  }
  {
    const int c00 = w*32 + lg*4, c01 = c00 + 16;
    float4 bx0 = *reinterpret_cast<const float4*>(xb1 + c00);
    float4 bx1 = *reinterpret_cast<const float4*>(xb1 + c01);
    float4 xw0 = *reinterpret_cast<const float4*>(xw2 + c00);
    float4 xw1v = *reinterpret_cast<const float4*>(xw2 + c01);
    float ql[4];
    #pragma unroll
    for (int t = 0; t < 4; ++t) {
      ql[t] = 0.f;
      #pragma unroll
      for (int j = 0; j < 2; ++j) {
        const float4 bx = j ? bx1 : bx0;
        const float4 xw = j ? xw1v : xw0;
        ql[t] += fmaxf(acc3[t][j][0] + bx.x, 0.f) * xw.x
               + fmaxf(acc3[t][j][1] + bx.y, 0.f) * xw.y
               + fmaxf(acc3[t][j][2] + bx.z, 0.f) * xw.z
               + fmaxf(acc3[t][j][3] + bx.w, 0.f) * xw.w;
      }
      ql[t] += __shfl_xor(ql[t], 16, 64);
      ql[t] += __shfl_xor(ql[t], 32, 64);
    }
    if (lane < 16) {
      #pragma unroll
      for (int t = 0; t < 4; ++t) ppart[w][t*16 + lane] = ql[t];
    }
  }
  __syncthreads();  // sync3: qpart ready

  if (tid < 192) {
    int row = tid / 3, c = tid - row*3;
    float q = ppart[0][row] + ppart[1][row] + ppart[2][row] + ppart[3][row] + xb2[0];
    atomicAdd(dx + dL[row]*3 + c, relL[row][c] * q);
  }
}

// ---- node kernel: h_new = h + MLP([mi,h]); x_new = x + dx ----
template<int MODE>
__global__ __launch_bounds__(256) void node_kernel(
    const float* __restrict__ h, const float* __restrict__ x,
    const float* __restrict__ nb1, const float* __restrict__ nb2,
    const short8* __restrict__ NW1p, const short8* __restrict__ NW2p,
    const unsigned short* __restrict__ miB,
    const unsigned short* __restrict__ hB,
    float* __restrict__ out) {
  __shared__ __align__(16) char c2B[64 * 512];  // [64][256] bf16, swizzled
  __shared__ __align__(16) char y3B[64 * 256];  // [64][128] bf16, swizzled
  const int tid = threadIdx.x;
  const int n0 = blockIdx.x * 64;
  const float* mi = out;

  for (int i = tid; i < 64*32; i += 256) {
    int row = i >> 5, c = i & 31;
    int node = n0 + row;
    U8 u;
    if (node < NNODES) {
      if (c < 16 && MODE >= 1) {
        u.v = *reinterpret_cast<const short8*>(miB + (size_t)node*128 + c*8);
      } else if (c >= 16 && MODE == 2) {
        u.v = *reinterpret_cast<const short8*>(hB + (size_t)node*128 + (c-16)*8);
      } else {
        const float4* p = (c < 16)
          ? reinterpret_cast<const float4*>(mi + (size_t)node*128 + c*8)
          : reinterpret_cast<const float4*>(h + (size_t)node*128 + (c-16)*8);
        float4 a = p[0], b = p[1];
        uint4 uu;
        uu.x = pk2(a.x, a.y); uu.y = pk2(a.z, a.w);
        uu.z = pk2(b.x, b.y); uu.w = pk2(b.z, b.w);
        u.v = *reinterpret_cast<short8*>(&uu);
      }
    } else {
      #pragma unroll
      for (int j = 0; j < 8; ++j) u.u[j] = 0;
    }
    *reinterpret_cast<short8*>(c2B + row*512 + ((c ^ (row&7))<<4)) = u.v;
  }
  __syncthreads();

  const int lane = tid & 63, wave = tid >> 6;
  const int lr = lane & 15, lg = lane >> 4;
  const int rb = wave * 16;
  const int arow = rb + lr;

  // GEMM n1: y3 = relu([mi,h] @ NW1 + nb1), K=256
  f32x4 acc[8];
  #pragma unroll
  for (int nt = 0; nt < 8; ++nt) acc[nt] = (f32x4)0.0f;
  #pragma unroll
  for (int kt = 0; kt < 8; ++kt) {
    int chunk = kt*4 + lg;
    short8 a = *reinterpret_cast<const short8*>(c2B + arow*512 + ((chunk ^ (arow&7))<<4));
    const short8* bp = NW1p + chunk*128 + lr;
    #pragma unroll
    for (int nt = 0; nt < 8; ++nt)
      acc[nt] = __builtin_amdgcn_mfma_f32_16x16x32_bf16(a, bp[nt*16], acc[nt], 0, 0, 0);
  }
  #pragma unroll
  for (int nt = 0; nt < 8; ++nt) {
    int col = nt*16 + lr;
    float bias = nb1[col];
    #pragma unroll
    for (int r = 0; r < 4; ++r) {
      int row = rb + lg*4 + r;
      float v = fmaxf(acc[nt][r] + bias, 0.f);
      *reinterpret_cast<unsigned short*>(y3B + row*256 + (((col>>3) ^ (row&7))<<4) + ((col&7)<<1)) = f2b(v);
    }
  }

  // GEMM n2: out = y3 @ NW2 + nb2 + h, K=128
  f32x4 acc2[8];
  #pragma unroll
  for (int nt = 0; nt < 8; ++nt) acc2[nt] = (f32x4)0.0f;
  #pragma unroll
  for (int kt = 0; kt < 4; ++kt) {
    int chunk = kt*4 + lg;
    short8 a = *reinterpret_cast<const short8*>(y3B + arow*256 + ((chunk ^ (arow&7))<<4));
    const short8* bp = NW2p + chunk*128 + lr;
    #pragma unroll
    for (int nt = 0; nt < 8; ++nt)
      acc2[nt] = __builtin_amdgcn_mfma_f32_16x16x32_bf16(a, bp[nt*16], acc2[nt], 0, 0, 0);
  }
  __syncthreads();  // ensure all mi reads (MODE=0 path reads out) done before overwrite
  #pragma unroll
  for (int nt = 0; nt < 8; ++nt) {
    int col = nt*16 + lr;
    float b2 = nb2[col];
    #pragma unroll
    for (int r = 0; r < 4; ++r) {
      int row = rb + lg*4 + r;
      int node = n0 + row;
      if (node < NNODES) {
        int idx = node*128 + col;
        out[idx] = acc2[nt][r] + b2 + h[idx];
      }
    }
  }

  if (tid < 192) {
    int node = n0 + tid/3;
    if (node < NNODES) {
      int idx = node*3 + (tid%3);
      float* xo = out + NNODES*HID;
      xo[idx] = x[idx] + xo[idx];
    }
  }
}

extern "C" void kernel_launch(void* const* d_in, const int* in_sizes, int n_in,
                              void* d_out, int out_size, void* d_ws, size_t ws_size,
                              hipStream_t stream) {
  const int*   src  = (const int*)  d_in[0];
  const int*   dst  = (const int*)  d_in[1];
  const float* ef   = (const float*)d_in[2];
  const float* h    = (const float*)d_in[3];
  const float* x    = (const float*)d_in[4];
  const float* ew1  = (const float*)d_in[5];
  const float* eb1  = (const float*)d_in[6];
  const float* ew2  = (const float*)d_in[7];
  const float* eb2  = (const float*)d_in[8];
  const float* infw = (const float*)d_in[9];
  const float* infb = (const float*)d_in[10];
  const float* xw1  = (const float*)d_in[11];
  const float* xb1  = (const float*)d_in[12];
  const float* xw2  = (const float*)d_in[13];
  const float* xb2  = (const float*)d_in[14];
  const float* nw1  = (const float*)d_in[15];
  const float* nb1  = (const float*)d_in[16];
  const float* nw2  = (const float*)d_in[17];
  const float* nb2  = (const float*)d_in[18];

  float* out = (float*)d_out;
  float* miF = out;                  // f32 fallback: mi accumulates where h_new will go
  float* dxp = out + NNODES*HID;     // delta_x accumulates where x_new will go
  unsigned short* wsp = (unsigned short*)d_ws;
  unsigned short* miB = wsp + 118784;
  unsigned short* hBp = miB + (size_t)NNODES*HID;

  const size_t MIN = (size_t)NNODES*HID;                 // 6.4M elems
  size_t need1 = (118784u + MIN) * 2u;                   // 13.04 MB
  size_t need2 = (118784u + 2u*MIN) * 2u;                // 25.84 MB
  int mode = (ws_size >= need2) ? 2 : (ws_size >= need1 ? 1 : 0);

  if (mode >= 1) {
    hipMemsetAsync(miB, 0, MIN*2, stream);
    hipMemsetAsync(dxp, 0, (size_t)NNODES*3*4, stream);
  } else {
    hipMemsetAsync(d_out, 0, (size_t)out_size * sizeof(float), stream);
  }

  pack_kernel<<<464, 256, 0, stream>>>(ew1, ew2, xw1, nw1, nw2, wsp);
  if (mode == 2) hpack_kernel<<<(NNODES*HID)/(256*8), 256, 0, stream>>>(h, hBp);

  if (mode == 2) {
    edge_kernel<2><<<NEDGES/64, 256, 0, stream>>>(
        src, dst, ef, h, x, eb1, eb2, infw, infb, xb1, xw2, xb2,
        (const short8*)wsp, (const short8*)(wsp + 36864), (const short8*)(wsp + 53248),
        hBp, miF, miB, dxp);
    node_kernel<2><<<(NNODES + 63)/64, 256, 0, stream>>>(
        h, x, nb1, nb2,
        (const short8*)(wsp + 69632), (const short8*)(wsp + 102400), miB, hBp, out);
  } else if (mode == 1) {
    edge_kernel<1><<<NEDGES/64, 256, 0, stream>>>(
        src, dst, ef, h, x, eb1, eb2, infw, infb, xb1, xw2, xb2,
        (const short8*)wsp, (const short8*)(wsp + 36864), (const short8*)(wsp + 53248),
        hBp, miF, miB, dxp);
    node_kernel<1><<<(NNODES + 63)/64, 256, 0, stream>>>(
        h, x, nb1, nb2,
        (const short8*)(wsp + 69632), (const short8*)(wsp + 102400), miB, hBp, out);
  } else {
    edge_kernel<0><<<NEDGES/64, 256, 0, stream>>>(
        src, dst, ef, h, x, eb1, eb2, infw, infb, xb1, xw2, xb2,
        (const short8*)wsp, (const short8*)(wsp + 36864), (const short8*)(wsp + 53248),
        hBp, miF, miB, dxp);
    node_kernel<0><<<(NNODES + 63)/64, 256, 0, stream>>>(
        h, x, nb1, nb2,
        (const short8*)(wsp + 69632), (const short8*)(wsp + 102400), miB, hBp, out);
  }
}

// Round 8
// 319.640 us; speedup vs baseline: 2.5469x; 2.5469x over previous
//
#include <hip/hip_runtime.h>

#define HID 128
#define NNODES 50000
#define NEDGES 800000

typedef __attribute__((ext_vector_type(8))) short short8;
typedef __attribute__((ext_vector_type(4))) float f32x4;

union U8 { short8 v; unsigned short u[8]; };

__device__ __forceinline__ unsigned short f2b(float f) {
  unsigned int u = __float_as_uint(f);
  u += 0x7FFFu + ((u >> 16) & 1u);
  return (unsigned short)(u >> 16);
}

// packed RNE f32->bf16x2 (lo = a, hi = b) — plain C.
// (inline-asm v_cvt_pk_bf16_f32 was proven WRONG on this target in r4 — do not reintroduce)
__device__ __forceinline__ unsigned int pk2(float a, float b) {
  unsigned int ua = __float_as_uint(a);
  ua += 0x7FFFu + ((ua >> 16) & 1u);
  unsigned int ub = __float_as_uint(b);
  ub += 0x7FFFu + ((ub >> 16) & 1u);
  return (ua >> 16) | (ub & 0xFFFF0000u);
}

// cheap round-half-up pack (tie behavior differs from RNE only)
__device__ __forceinline__ unsigned int pk2h(float a, float b) {
  unsigned int ua = __float_as_uint(a) + 0x8000u;
  unsigned int ub = __float_as_uint(b) + 0x8000u;
  return (ua >> 16) | (ub & 0xFFFF0000u);
}

// packed bf16 atomic add: mem[addr] += lo, mem[addr+2] += hi  (gfx950 ISA; verified r3)
__device__ __forceinline__ void atomicPkAddBf16(unsigned short* addr, unsigned int packed) {
  asm volatile("global_atomic_pk_add_bf16 %0, %1, off" :: "v"(addr), "v"(packed) : "memory");
}

// ---- pack weights into bf16 fragment-native layout ----
__global__ __launch_bounds__(256) void pack_kernel(
    const float* __restrict__ ew1, const float* __restrict__ ew2,
    const float* __restrict__ xw1, const float* __restrict__ nw1,
    const float* __restrict__ nw2, unsigned short* __restrict__ ws) {
  int i = blockIdx.x * 256 + threadIdx.x;
  const float* w; int base, ksrc;
  if (i < 36864)       { w = ew1; base = 0;      ksrc = 280; }
  else if (i < 53248)  { w = ew2; base = 36864;  ksrc = 128; }
  else if (i < 69632)  { w = xw1; base = 53248;  ksrc = 128; }
  else if (i < 102400) { w = nw1; base = 69632;  ksrc = 256; }
  else if (i < 118784) { w = nw2; base = 102400; ksrc = 128; }
  else return;
  int li = i - base;
  int j = li & 7, t = li >> 3;
  int col = t & 127, kg = t >> 7;
  int k = kg * 8 + j;
  float v = (k < ksrc) ? w[k * 128 + col] : 0.0f;
  ws[i] = f2b(v);
}

// ---- pre-convert h (f32 [NNODES][128]) to bf16 copy hB ----
__global__ __launch_bounds__(256) void hpack_kernel(
    const float* __restrict__ h, unsigned short* __restrict__ hB) {
  int i = blockIdx.x * 256 + threadIdx.x;  // handles 8 elements
  const float4* p = reinterpret_cast<const float4*>(h + (size_t)i * 8);
  float4 a = p[0], b = p[1];
  uint4 u;
  u.x = pk2(a.x, a.y); u.y = pk2(a.z, a.w);
  u.z = pk2(b.x, b.y); u.w = pk2(b.z, b.w);
  *reinterpret_cast<uint4*>(hB + (size_t)i * 8) = u;
}

// ---- edge kernel: 64 edges/block, N-split waves, SWAPPED-OPERAND MFMA ----
// mfma(A=weight_frag, B=cat_frag): D[wcol][edge]; lane holds edge=lane&15,
// wcols = w*32 + j*16 + (lane>>4)*4 + {0..3}. Epilogues need no shfl pairing.
// Scatter: u=mij*eij staged into dead y1 zone (chunks 0..15), read back in the
// coalesced r6 shape (4 dst rows x 16 consecutive dwords per wave instr).
template<int MODE>
__global__ __launch_bounds__(256, 4) void edge_kernel(
    const int* __restrict__ src, const int* __restrict__ dst,
    const float* __restrict__ ef, const float* __restrict__ h,
    const float* __restrict__ x,
    const float* __restrict__ eb1, const float* __restrict__ eb2,
    const float* __restrict__ infw, const float* __restrict__ infb,
    const float* __restrict__ xb1, const float* __restrict__ xw2,
    const float* __restrict__ xb2,
    const short8* __restrict__ W1p, const short8* __restrict__ W2p,
    const short8* __restrict__ XW1p,
    const unsigned short* __restrict__ hB,
    float* __restrict__ miF, unsigned short* __restrict__ miB,
    float* __restrict__ dx) {
  __shared__ __align__(16) char catB[64 * 576];
  __shared__ int dL[64], sL[64];
  __shared__ float relL[64][3];
  __shared__ float ppart[4][64];   // reused as qpart
  __shared__ float eijL[64];

  const int tid = threadIdx.x;
  const int e0 = blockIdx.x * 64;
  const int lane = tid & 63, w = tid >> 6;
  const int lr = lane & 15, lg = lane >> 4;
  const int l7 = lr & 7, l3 = lr & 3;
  const int colb = w*32 + lr;      // weight-frag col

  // phase 0 (distributed, 4 threads/edge)
  {
    int row = tid >> 2, sub = tid & 3;
    int e = e0 + row;
    int s = src[e], d = dst[e];
    if (sub == 0) { sL[row] = s; dL[row] = d; }
    float rx = x[3*d+0] - x[3*s+0];
    float ry = x[3*d+1] - x[3*s+1];
    float rz = x[3*d+2] - x[3*s+2];
    if (sub == 1) { relL[row][0] = rx; relL[row][1] = ry; relL[row][2] = rz; }
    float r = rx*rx + ry*ry + rz*rz;
    const float step = 100.0f / 19.0f;
    const float co = -0.5f / (step * step);
    float v6[6];
    if (sub == 0) {
      const float4 efv = reinterpret_cast<const float4*>(ef)[e];
      v6[0]=efv.x; v6[1]=efv.y; v6[2]=efv.z; v6[3]=efv.w;
      float t1 = r - step;
      v6[4] = __expf(co * r * r);
      v6[5] = __expf(co * t1 * t1);
    } else {
      #pragma unroll
      for (int q = 0; q < 6; ++q) {
        float g = (float)(sub*6 - 4 + q) * step;
        float t = r - g;
        v6[q] = __expf(co * t * t);
      }
    }
    #pragma unroll
    for (int q = 0; q < 3; ++q) {
      int c = sub*6 + q*2;
      int chunk = (c>>3) ^ (row&7);
      *reinterpret_cast<unsigned int*>(catB + row*576 + (chunk<<4) + ((c&7)<<1)) = pk2h(v6[q*2], v6[q*2+1]);
    }
    if (sub == 3) {
      U8 z;
      #pragma unroll
      for (int j = 0; j < 8; ++j) z.u[j] = 0;
      *reinterpret_cast<short8*>(catB + row*576 + ((32 + (3 ^ (row&3)))<<4)) = z.v;
    }
  }

  // gather h[dst] (chunks 3..18) and h[src] (chunks 19..34)
  #pragma unroll
  for (int it = 0; it < 8; ++it) {
    int i = tid + it*256;
    int row = i >> 5, c = i & 31;
    int node = (c < 16) ? dst[e0+row] : src[e0+row];
    int chunk = 3 + c;
    int sw = (chunk < 32) ? (chunk ^ (row&7)) : (32 + ((chunk&3) ^ (row&3)));
    if (MODE == 2) {
      short8 u = *reinterpret_cast<const short8*>(hB + (size_t)node*128 + (c&15)*8);
      *reinterpret_cast<short8*>(catB + row*576 + (sw<<4)) = u;
    } else {
      const float4* hp = reinterpret_cast<const float4*>(h + (size_t)node*128 + (c&15)*8);
      float4 a = hp[0], b = hp[1];
      uint4 u;
      u.x = pk2(a.x, a.y); u.y = pk2(a.z, a.w);
      u.z = pk2(b.x, b.y); u.w = pk2(b.z, b.w);
      *reinterpret_cast<uint4*>(catB + row*576 + (sw<<4)) = u;
    }
  }

  // prefetch GEMM1 weight fragments for kt=0,1
  short8 p00 = W1p[(0*4+lg)*128 + colb], p01 = W1p[(0*4+lg)*128 + colb + 16];
  short8 p10 = W1p[(1*4+lg)*128 + colb], p11 = W1p[(1*4+lg)*128 + colb + 16];
  __syncthreads();

  // ---- GEMM1: y1 = relu(cat @ W1 + eb1), K=288 (swapped: D[wcol][edge]) ----
  f32x4 acc[4][2];
  #pragma unroll
  for (int t = 0; t < 4; ++t) { acc[t][0] = (f32x4)0.0f; acc[t][1] = (f32x4)0.0f; }
  #pragma unroll
  for (int kt = 0; kt < 9; ++kt) {
    int ch = (kt < 8) ? ((kt*4+lg) ^ l7) : (32 + (lg ^ l3));
    short8 a0 = *reinterpret_cast<const short8*>(catB + (0*16+lr)*576 + (ch<<4));
    short8 a1 = *reinterpret_cast<const short8*>(catB + (1*16+lr)*576 + (ch<<4));
    short8 a2 = *reinterpret_cast<const short8*>(catB + (2*16+lr)*576 + (ch<<4));
    short8 a3 = *reinterpret_cast<const short8*>(catB + (3*16+lr)*576 + (ch<<4));
    short8 b0, b1;
    if (kt == 0)      { b0 = p00; b1 = p01; }
    else if (kt == 1) { b0 = p10; b1 = p11; }
    else              { b0 = W1p[(kt*4+lg)*128 + colb]; b1 = W1p[(kt*4+lg)*128 + colb + 16]; }
    acc[0][0] = __builtin_amdgcn_mfma_f32_16x16x32_bf16(b0, a0, acc[0][0], 0, 0, 0);
    acc[0][1] = __builtin_amdgcn_mfma_f32_16x16x32_bf16(b1, a0, acc[0][1], 0, 0, 0);
    acc[1][0] = __builtin_amdgcn_mfma_f32_16x16x32_bf16(b0, a1, acc[1][0], 0, 0, 0);
    acc[1][1] = __builtin_amdgcn_mfma_f32_16x16x32_bf16(b1, a1, acc[1][1], 0, 0, 0);
    acc[2][0] = __builtin_amdgcn_mfma_f32_16x16x32_bf16(b0, a2, acc[2][0], 0, 0, 0);
    acc[2][1] = __builtin_amdgcn_mfma_f32_16x16x32_bf16(b1, a2, acc[2][1], 0, 0, 0);
    acc[3][0] = __builtin_amdgcn_mfma_f32_16x16x32_bf16(b0, a3, acc[3][0], 0, 0, 0);
    acc[3][1] = __builtin_amdgcn_mfma_f32_16x16x32_bf16(b1, a3, acc[3][1], 0, 0, 0);
  }
  __syncthreads();  // all cat reads complete before y1 overwrites zone A

  // y1 epilogue: lane holds edge t*16+lr, cols c0j = w*32+j*16+lg*4+{0..3}
  {
    const int c00 = w*32 + lg*4, c01 = c00 + 16;
    float4 be0 = *reinterpret_cast<const float4*>(eb1 + c00);
    float4 be1 = *reinterpret_cast<const float4*>(eb1 + c01);
    #pragma unroll
    for (int t = 0; t < 4; ++t) {
      int row = t*16 + lr;
      char* rowB = catB + row*576;
      #pragma unroll
      for (int j = 0; j < 2; ++j) {
        const float4 be = j ? be1 : be0;
        int c0 = j ? c01 : c00;
        float v0 = fmaxf(acc[t][j][0] + be.x, 0.f);
        float v1 = fmaxf(acc[t][j][1] + be.y, 0.f);
        float v2 = fmaxf(acc[t][j][2] + be.z, 0.f);
        float v3 = fmaxf(acc[t][j][3] + be.w, 0.f);
        uint2 pv; pv.x = pk2h(v0, v1); pv.y = pk2h(v2, v3);
        int chunk = (c0>>3) ^ (row&7);
        *reinterpret_cast<uint2*>(rowB + (chunk<<4) + ((c0&7)<<1)) = pv;
      }
    }
  }
  __syncthreads();  // y1 visible to all waves

  // ---- GEMM2: mij = relu(y1 @ W2 + eb2), K=128 ----
  f32x4 acc2[4][2];
  #pragma unroll
  for (int t = 0; t < 4; ++t) { acc2[t][0] = (f32x4)0.0f; acc2[t][1] = (f32x4)0.0f; }
  #pragma unroll
  for (int kt = 0; kt < 4; ++kt) {
    int ch = (kt*4+lg) ^ l7;
    short8 a0 = *reinterpret_cast<const short8*>(catB + (0*16+lr)*576 + (ch<<4));
    short8 a1 = *reinterpret_cast<const short8*>(catB + (1*16+lr)*576 + (ch<<4));
    short8 a2 = *reinterpret_cast<const short8*>(catB + (2*16+lr)*576 + (ch<<4));
    short8 a3 = *reinterpret_cast<const short8*>(catB + (3*16+lr)*576 + (ch<<4));
    short8 b0 = W2p[(kt*4+lg)*128 + colb];
    short8 b1 = W2p[(kt*4+lg)*128 + colb + 16];
    acc2[0][0] = __builtin_amdgcn_mfma_f32_16x16x32_bf16(b0, a0, acc2[0][0], 0, 0, 0);
    acc2[0][1] = __builtin_amdgcn_mfma_f32_16x16x32_bf16(b1, a0, acc2[0][1], 0, 0, 0);
    acc2[1][0] = __builtin_amdgcn_mfma_f32_16x16x32_bf16(b0, a1, acc2[1][0], 0, 0, 0);
    acc2[1][1] = __builtin_amdgcn_mfma_f32_16x16x32_bf16(b1, a1, acc2[1][1], 0, 0, 0);
    acc2[2][0] = __builtin_amdgcn_mfma_f32_16x16x32_bf16(b0, a2, acc2[2][0], 0, 0, 0);
    acc2[2][1] = __builtin_amdgcn_mfma_f32_16x16x32_bf16(b1, a2, acc2[2][1], 0, 0, 0);
    acc2[3][0] = __builtin_amdgcn_mfma_f32_16x16x32_bf16(b0, a3, acc2[3][0], 0, 0, 0);
    acc2[3][1] = __builtin_amdgcn_mfma_f32_16x16x32_bf16(b1, a3, acc2[3][1], 0, 0, 0);
  }
  // epilogue: mval kept in acc2; mij -> chunks 16..31; per-edge inf partials
  float pl[4];
  {
    const int c00 = w*32 + lg*4, c01 = c00 + 16;
    float4 be0 = *reinterpret_cast<const float4*>(eb2 + c00);
    float4 be1 = *reinterpret_cast<const float4*>(eb2 + c01);
    float4 iw0 = *reinterpret_cast<const float4*>(infw + c00);
    float4 iw1 = *reinterpret_cast<const float4*>(infw + c01);
    #pragma unroll
    for (int t = 0; t < 4; ++t) {
      int row = t*16 + lr;
      char* rowB = catB + row*576;
      pl[t] = 0.f;
      #pragma unroll
      for (int j = 0; j < 2; ++j) {
        const float4 be = j ? be1 : be0;
        const float4 iw = j ? iw1 : iw0;
        int c0 = j ? c01 : c00;
        float v0 = fmaxf(acc2[t][j][0] + be.x, 0.f);
        float v1 = fmaxf(acc2[t][j][1] + be.y, 0.f);
        float v2 = fmaxf(acc2[t][j][2] + be.z, 0.f);
        float v3 = fmaxf(acc2[t][j][3] + be.w, 0.f);
        acc2[t][j][0] = v0; acc2[t][j][1] = v1; acc2[t][j][2] = v2; acc2[t][j][3] = v3;
        pl[t] += v0*iw.x + v1*iw.y + v2*iw.z + v3*iw.w;
        uint2 pv; pv.x = pk2h(v0, v1); pv.y = pk2h(v2, v3);
        int chunk = 16 + ((c0>>3) ^ (row&7));
        *reinterpret_cast<uint2*>(rowB + (chunk<<4) + ((c0&7)<<1)) = pv;
      }
    }
    #pragma unroll
    for (int t = 0; t < 4; ++t) {
      pl[t] += __shfl_xor(pl[t], 16, 64);
      pl[t] += __shfl_xor(pl[t], 32, 64);
    }
    if (lane < 16) {
      #pragma unroll
      for (int t = 0; t < 4; ++t) ppart[w][t*16 + lane] = pl[t];
    }
  }
  __syncthreads();  // sync1: mij + ppart ready

  if (lane < 16) {
    int row2 = w*16 + lane;
    float s2 = ppart[0][row2] + ppart[1][row2] + ppart[2][row2] + ppart[3][row2] + infb[0];
    eijL[row2] = 1.f / (1.f + __expf(-s2));
  }
  __syncthreads();  // sync2: eijL ready

  // ---- stage u = mij*eij into dead y1 zone (chunks 0..15), bf16 ----
  if (MODE >= 1) {
    const int c00 = w*32 + lg*4, c01 = c00 + 16;
    #pragma unroll
    for (int t = 0; t < 4; ++t) {
      int row = t*16 + lr;
      float e = eijL[row];
      char* rowB = catB + row*576;
      #pragma unroll
      for (int j = 0; j < 2; ++j) {
        int c0 = j ? c01 : c00;
        uint2 pv;
        pv.x = pk2h(acc2[t][j][0]*e, acc2[t][j][1]*e);
        pv.y = pk2h(acc2[t][j][2]*e, acc2[t][j][3]*e);
        int chunk = (c0>>3) ^ (row&7);
        *reinterpret_cast<uint2*>(rowB + (chunk<<4) + ((c0&7)<<1)) = pv;
      }
    }
  } else {
    // f32 fallback: direct atomics (shape suboptimal but correct)
    const int c00 = w*32 + lg*4, c01 = c00 + 16;
    #pragma unroll
    for (int t = 0; t < 4; ++t) {
      int row = t*16 + lr;
      int d = dL[row];
      float e = eijL[row];
      float* fp = miF + (size_t)d*128;
      #pragma unroll
      for (int j = 0; j < 2; ++j) {
        int c0 = j ? c01 : c00;
        #pragma unroll
        for (int rg = 0; rg < 4; ++rg) atomicAdd(fp + c0 + rg, acc2[t][j][rg]*e);
      }
    }
  }
  __syncthreads();  // sync2b: u staged (no-op hazard for MODE=0, kept for uniformity)

  // ---- GEMM3: y2 = relu(mij @ XW1 + xb1); x_scale = y2 . xw2 + xb2 ----
  f32x4 acc3[4][2];
  #pragma unroll
  for (int t = 0; t < 4; ++t) { acc3[t][0] = (f32x4)0.0f; acc3[t][1] = (f32x4)0.0f; }
  #pragma unroll
  for (int kt = 0; kt < 4; ++kt) {
    int ch = 16 + ((kt*4+lg) ^ l7);
    short8 a0 = *reinterpret_cast<const short8*>(catB + (0*16+lr)*576 + (ch<<4));
    short8 a1 = *reinterpret_cast<const short8*>(catB + (1*16+lr)*576 + (ch<<4));
    short8 a2 = *reinterpret_cast<const short8*>(catB + (2*16+lr)*576 + (ch<<4));
    short8 a3 = *reinterpret_cast<const short8*>(catB + (3*16+lr)*576 + (ch<<4));
    short8 b0 = XW1p[(kt*4+lg)*128 + colb];
    short8 b1 = XW1p[(kt*4+lg)*128 + colb + 16];
    acc3[0][0] = __builtin_amdgcn_mfma_f32_16x16x32_bf16(b0, a0, acc3[0][0], 0, 0, 0);
    acc3[0][1] = __builtin_amdgcn_mfma_f32_16x16x32_bf16(b1, a0, acc3[0][1], 0, 0, 0);
    acc3[1][0] = __builtin_amdgcn_mfma_f32_16x16x32_bf16(b0, a1, acc3[1][0], 0, 0, 0);
    acc3[1][1] = __builtin_amdgcn_mfma_f32_16x16x32_bf16(b1, a1, acc3[1][1], 0, 0, 0);
    acc3[2][0] = __builtin_amdgcn_mfma_f32_16x16x32_bf16(b0, a2, acc3[2][0], 0, 0, 0);
    acc3[2][1] = __builtin_amdgcn_mfma_f32_16x16x32_bf16(b1, a2, acc3[2][1], 0, 0, 0);
    acc3[3][0] = __builtin_amdgcn_mfma_f32_16x16x32_bf16(b0, a3, acc3[3][0], 0, 0, 0);
    acc3[3][1] = __builtin_amdgcn_mfma_f32_16x16x32_bf16(b1, a3, acc3[3][1], 0, 0, 0);
  }

  // ---- coalesced scatter: read staged u, pk-atomic to miB ----
  // per wave instr: 4 dst rows (lg) x 16 consecutive dwords (lr) — r6 shape
  if (MODE >= 1) {
    #pragma unroll
    for (int t = 0; t < 4; ++t)
      #pragma unroll
      for (int rg = 0; rg < 4; ++rg) {
        int row = t*16 + lg*4 + rg;
        int d = dL[row];
        int col0 = w*32 + lr*2;
        unsigned int val = *reinterpret_cast<const unsigned int*>(
            catB + row*576 + (((col0>>3) ^ (row&7))<<4) + ((col0&7)<<1));
        if (val) atomicPkAddBf16(miB + (size_t)d*128 + col0, val);
      }
  }

  // GEMM3 epilogue: x_scale reduce
  {
    const int c00 = w*32 + lg*4, c01 = c00 + 16;
    float4 bx0 = *reinterpret_cast<const float4*>(xb1 + c00);
    float4 bx1 = *reinterpret_cast<const float4*>(xb1 + c01);
    float4 xw0 = *reinterpret_cast<const float4*>(xw2 + c00);
    float4 xw1v = *reinterpret_cast<const float4*>(xw2 + c01);
    float ql[4];
    #pragma unroll
    for (int t = 0; t < 4; ++t) {
      ql[t] = 0.f;
      #pragma unroll
      for (int j = 0; j < 2; ++j) {
        const float4 bx = j ? bx1 : bx0;
        const float4 xw = j ? xw1v : xw0;
        ql[t] += fmaxf(acc3[t][j][0] + bx.x, 0.f) * xw.x
               + fmaxf(acc3[t][j][1] + bx.y, 0.f) * xw.y
               + fmaxf(acc3[t][j][2] + bx.z, 0.f) * xw.z
               + fmaxf(acc3[t][j][3] + bx.w, 0.f) * xw.w;
      }
      ql[t] += __shfl_xor(ql[t], 16, 64);
      ql[t] += __shfl_xor(ql[t], 32, 64);
    }
    if (lane < 16) {
      #pragma unroll
      for (int t = 0; t < 4; ++t) ppart[w][t*16 + lane] = ql[t];
    }
  }
  __syncthreads();  // sync3: qpart ready

  if (tid < 192) {
    int row = tid / 3, c = tid - row*3;
    float q = ppart[0][row] + ppart[1][row] + ppart[2][row] + ppart[3][row] + xb2[0];
    atomicAdd(dx + dL[row]*3 + c, relL[row][c] * q);
  }
}

// ---- node kernel: h_new = h + MLP([mi,h]); x_new = x + dx ----
template<int MODE>
__global__ __launch_bounds__(256) void node_kernel(
    const float* __restrict__ h, const float* __restrict__ x,
    const float* __restrict__ nb1, const float* __restrict__ nb2,
    const short8* __restrict__ NW1p, const short8* __restrict__ NW2p,
    const unsigned short* __restrict__ miB,
    const unsigned short* __restrict__ hB,
    float* __restrict__ out) {
  __shared__ __align__(16) char c2B[64 * 512];  // [64][256] bf16, swizzled
  __shared__ __align__(16) char y3B[64 * 256];  // [64][128] bf16, swizzled
  const int tid = threadIdx.x;
  const int n0 = blockIdx.x * 64;
  const float* mi = out;

  for (int i = tid; i < 64*32; i += 256) {
    int row = i >> 5, c = i & 31;
    int node = n0 + row;
    U8 u;
    if (node < NNODES) {
      if (c < 16 && MODE >= 1) {
        u.v = *reinterpret_cast<const short8*>(miB + (size_t)node*128 + c*8);
      } else if (c >= 16 && MODE == 2) {
        u.v = *reinterpret_cast<const short8*>(hB + (size_t)node*128 + (c-16)*8);
      } else {
        const float4* p = (c < 16)
          ? reinterpret_cast<const float4*>(mi + (size_t)node*128 + c*8)
          : reinterpret_cast<const float4*>(h + (size_t)node*128 + (c-16)*8);
        float4 a = p[0], b = p[1];
        uint4 uu;
        uu.x = pk2(a.x, a.y); uu.y = pk2(a.z, a.w);
        uu.z = pk2(b.x, b.y); uu.w = pk2(b.z, b.w);
        u.v = *reinterpret_cast<short8*>(&uu);
      }
    } else {
      #pragma unroll
      for (int j = 0; j < 8; ++j) u.u[j] = 0;
    }
    *reinterpret_cast<short8*>(c2B + row*512 + ((c ^ (row&7))<<4)) = u.v;
  }
  __syncthreads();

  const int lane = tid & 63, wave = tid >> 6;
  const int lr = lane & 15, lg = lane >> 4;
  const int rb = wave * 16;
  const int arow = rb + lr;

  // GEMM n1: y3 = relu([mi,h] @ NW1 + nb1), K=256
  f32x4 acc[8];
  #pragma unroll
  for (int nt = 0; nt < 8; ++nt) acc[nt] = (f32x4)0.0f;
  #pragma unroll
  for (int kt = 0; kt < 8; ++kt) {
    int chunk = kt*4 + lg;
    short8 a = *reinterpret_cast<const short8*>(c2B + arow*512 + ((chunk ^ (arow&7))<<4));
    const short8* bp = NW1p + chunk*128 + lr;
    #pragma unroll
    for (int nt = 0; nt < 8; ++nt)
      acc[nt] = __builtin_amdgcn_mfma_f32_16x16x32_bf16(a, bp[nt*16], acc[nt], 0, 0, 0);
  }
  #pragma unroll
  for (int nt = 0; nt < 8; ++nt) {
    int col = nt*16 + lr;
    float bias = nb1[col];
    #pragma unroll
    for (int r = 0; r < 4; ++r) {
      int row = rb + lg*4 + r;
      float v = fmaxf(acc[nt][r] + bias, 0.f);
      *reinterpret_cast<unsigned short*>(y3B + row*256 + (((col>>3) ^ (row&7))<<4) + ((col&7)<<1)) = f2b(v);
    }
  }

  // GEMM n2: out = y3 @ NW2 + nb2 + h, K=128
  f32x4 acc2[8];
  #pragma unroll
  for (int nt = 0; nt < 8; ++nt) acc2[nt] = (f32x4)0.0f;
  #pragma unroll
  for (int kt = 0; kt < 4; ++kt) {
    int chunk = kt*4 + lg;
    short8 a = *reinterpret_cast<const short8*>(y3B + arow*256 + ((chunk ^ (arow&7))<<4));
    const short8* bp = NW2p + chunk*128 + lr;
    #pragma unroll
    for (int nt = 0; nt < 8; ++nt)
      acc2[nt] = __builtin_amdgcn_mfma_f32_16x16x32_bf16(a, bp[nt*16], acc2[nt], 0, 0, 0);
  }
  __syncthreads();  // ensure all mi reads (MODE=0 path reads out) done before overwrite
  #pragma unroll
  for (int nt = 0; nt < 8; ++nt) {
    int col = nt*16 + lr;
    float b2 = nb2[col];
    #pragma unroll
    for (int r = 0; r < 4; ++r) {
      int row = rb + lg*4 + r;
      int node = n0 + row;
      if (node < NNODES) {
        int idx = node*128 + col;
        out[idx] = acc2[nt][r] + b2 + h[idx];
      }
    }
  }

  if (tid < 192) {
    int node = n0 + tid/3;
    if (node < NNODES) {
      int idx = node*3 + (tid%3);
      float* xo = out + NNODES*HID;
      xo[idx] = x[idx] + xo[idx];
    }
  }
}

extern "C" void kernel_launch(void* const* d_in, const int* in_sizes, int n_in,
                              void* d_out, int out_size, void* d_ws, size_t ws_size,
                              hipStream_t stream) {
  const int*   src  = (const int*)  d_in[0];
  const int*   dst  = (const int*)  d_in[1];
  const float* ef   = (const float*)d_in[2];
  const float* h    = (const float*)d_in[3];
  const float* x    = (const float*)d_in[4];
  const float* ew1  = (const float*)d_in[5];
  const float* eb1  = (const float*)d_in[6];
  const float* ew2  = (const float*)d_in[7];
  const float* eb2  = (const float*)d_in[8];
  const float* infw = (const float*)d_in[9];
  const float* infb = (const float*)d_in[10];
  const float* xw1  = (const float*)d_in[11];
  const float* xb1  = (const float*)d_in[12];
  const float* xw2  = (const float*)d_in[13];
  const float* xb2  = (const float*)d_in[14];
  const float* nw1  = (const float*)d_in[15];
  const float* nb1  = (const float*)d_in[16];
  const float* nw2  = (const float*)d_in[17];
  const float* nb2  = (const float*)d_in[18];

  float* out = (float*)d_out;
  float* miF = out;                  // f32 fallback
  float* dxp = out + NNODES*HID;
  unsigned short* wsp = (unsigned short*)d_ws;
  unsigned short* miB = wsp + 118784;
  unsigned short* hBp = miB + (size_t)NNODES*HID;

  const size_t MIN = (size_t)NNODES*HID;
  size_t need1 = (118784u + MIN) * 2u;
  size_t need2 = (118784u + 2u*MIN) * 2u;
  int mode = (ws_size >= need2) ? 2 : (ws_size >= need1 ? 1 : 0);

  if (mode >= 1) {
    hipMemsetAsync(miB, 0, MIN*2, stream);
    hipMemsetAsync(dxp, 0, (size_t)NNODES*3*4, stream);
  } else {
    hipMemsetAsync(d_out, 0, (size_t)out_size * sizeof(float), stream);
  }

  pack_kernel<<<464, 256, 0, stream>>>(ew1, ew2, xw1, nw1, nw2, wsp);
  if (mode == 2) hpack_kernel<<<(NNODES*HID)/(256*8), 256, 0, stream>>>(h, hBp);

  if (mode == 2) {
    edge_kernel<2><<<NEDGES/64, 256, 0, stream>>>(
        src, dst, ef, h, x, eb1, eb2, infw, infb, xb1, xw2, xb2,
        (const short8*)wsp, (const short8*)(wsp + 36864), (const short8*)(wsp + 53248),
        hBp, miF, miB, dxp);
    node_kernel<2><<<(NNODES + 63)/64, 256, 0, stream>>>(
        h, x, nb1, nb2,
        (const short8*)(wsp + 69632), (const short8*)(wsp + 102400), miB, hBp, out);
  } else if (mode == 1) {
    edge_kernel<1><<<NEDGES/64, 256, 0, stream>>>(
        src, dst, ef, h, x, eb1, eb2, infw, infb, xb1, xw2, xb2,
        (const short8*)wsp, (const short8*)(wsp + 36864), (const short8*)(wsp + 53248),
        hBp, miF, miB, dxp);
    node_kernel<1><<<(NNODES + 63)/64, 256, 0, stream>>>(
        h, x, nb1, nb2,
        (const short8*)(wsp + 69632), (const short8*)(wsp + 102400), miB, hBp, out);
  } else {
    edge_kernel<0><<<NEDGES/64, 256, 0, stream>>>(
        src, dst, ef, h, x, eb1, eb2, infw, infb, xb1, xw2, xb2,
        (const short8*)wsp, (const short8*)(wsp + 36864), (const short8*)(wsp + 53248),
        hBp, miF, miB, dxp);
    node_kernel<0><<<(NNODES + 63)/64, 256, 0, stream>>>(
        h, x, nb1, nb2,
        (const short8*)(wsp + 69632), (const short8*)(wsp + 102400), miB, hBp, out);
  }
}

// Round 9
// 314.435 us; speedup vs baseline: 2.5891x; 1.0166x over previous
//
#include <hip/hip_runtime.h>

#define HID 128
#define NNODES 50000
#define NEDGES 800000

typedef __attribute__((ext_vector_type(8))) short short8;
typedef __attribute__((ext_vector_type(4))) float f32x4;

union U8 { short8 v; unsigned short u[8]; };

__device__ __forceinline__ unsigned short f2b(float f) {
  unsigned int u = __float_as_uint(f);
  u += 0x7FFFu + ((u >> 16) & 1u);
  return (unsigned short)(u >> 16);
}

// packed RNE f32->bf16x2 (lo = a, hi = b) — plain C.
// (inline-asm v_cvt_pk_bf16_f32 was proven WRONG on this target in r4 — do not reintroduce)
__device__ __forceinline__ unsigned int pk2(float a, float b) {
  unsigned int ua = __float_as_uint(a);
  ua += 0x7FFFu + ((ua >> 16) & 1u);
  unsigned int ub = __float_as_uint(b);
  ub += 0x7FFFu + ((ub >> 16) & 1u);
  return (ua >> 16) | (ub & 0xFFFF0000u);
}

// cheap round-half-up pack (tie behavior differs from RNE only)
__device__ __forceinline__ unsigned int pk2h(float a, float b) {
  unsigned int ua = __float_as_uint(a) + 0x8000u;
  unsigned int ub = __float_as_uint(b) + 0x8000u;
  return (ua >> 16) | (ub & 0xFFFF0000u);
}

// packed bf16 atomic add: mem[addr] += lo, mem[addr+2] += hi  (gfx950 ISA; verified r3)
__device__ __forceinline__ void atomicPkAddBf16(unsigned short* addr, unsigned int packed) {
  asm volatile("global_atomic_pk_add_bf16 %0, %1, off" :: "v"(addr), "v"(packed) : "memory");
}

// stage-zone swizzle (chunks 0..15): conflict-free for scatter's 4-rows-differing-by-4
// read pattern. Bijective per row (XOR of constants), used by BOTH write and read.
__device__ __forceinline__ int stage_chunk(int c0, int row) {
  return ((c0 >> 3) ^ (row & 7) ^ (((row >> 2) & 3) << 1)) & 15;
}

// ---- pack weights into bf16 fragment-native layout ----
__global__ __launch_bounds__(256) void pack_kernel(
    const float* __restrict__ ew1, const float* __restrict__ ew2,
    const float* __restrict__ xw1, const float* __restrict__ nw1,
    const float* __restrict__ nw2, unsigned short* __restrict__ ws) {
  int i = blockIdx.x * 256 + threadIdx.x;
  const float* w; int base, ksrc;
  if (i < 36864)       { w = ew1; base = 0;      ksrc = 280; }
  else if (i < 53248)  { w = ew2; base = 36864;  ksrc = 128; }
  else if (i < 69632)  { w = xw1; base = 53248;  ksrc = 128; }
  else if (i < 102400) { w = nw1; base = 69632;  ksrc = 256; }
  else if (i < 118784) { w = nw2; base = 102400; ksrc = 128; }
  else return;
  int li = i - base;
  int j = li & 7, t = li >> 3;
  int col = t & 127, kg = t >> 7;
  int k = kg * 8 + j;
  float v = (k < ksrc) ? w[k * 128 + col] : 0.0f;
  ws[i] = f2b(v);
}

// ---- pre-convert h (f32 [NNODES][128]) to bf16 copy hB ----
__global__ __launch_bounds__(256) void hpack_kernel(
    const float* __restrict__ h, unsigned short* __restrict__ hB) {
  int i = blockIdx.x * 256 + threadIdx.x;  // handles 8 elements
  const float4* p = reinterpret_cast<const float4*>(h + (size_t)i * 8);
  float4 a = p[0], b = p[1];
  uint4 u;
  u.x = pk2(a.x, a.y); u.y = pk2(a.z, a.w);
  u.z = pk2(b.x, b.y); u.w = pk2(b.z, b.w);
  *reinterpret_cast<uint4*>(hB + (size_t)i * 8) = u;
}

// ---- edge kernel: 64 edges/block, N-split waves, SWAPPED-OPERAND MFMA ----
// mfma(A=weight_frag, B=cat_frag): D[wcol][edge]; lane holds edge=lane&15,
// wcols = w*32 + j*16 + (lane>>4)*4 + {0..3}.
// Scatter: u=mij*eij staged into dead y1 zone (chunks 0..15, stage_chunk swizzle),
// read back in the coalesced shape (4 dst rows x 16 consecutive dwords per wave
// instr), issued BEFORE GEMM3 so GEMM3 hides atomic latency.
template<int MODE>
__global__ __launch_bounds__(256, 4) void edge_kernel(
    const int* __restrict__ src, const int* __restrict__ dst,
    const float* __restrict__ ef, const float* __restrict__ h,
    const float* __restrict__ x,
    const float* __restrict__ eb1, const float* __restrict__ eb2,
    const float* __restrict__ infw, const float* __restrict__ infb,
    const float* __restrict__ xb1, const float* __restrict__ xw2,
    const float* __restrict__ xb2,
    const short8* __restrict__ W1p, const short8* __restrict__ W2p,
    const short8* __restrict__ XW1p,
    const unsigned short* __restrict__ hB,
    float* __restrict__ miF, unsigned short* __restrict__ miB,
    float* __restrict__ dx) {
  __shared__ __align__(16) char catB[64 * 576];
  __shared__ int dL[64], sL[64];
  __shared__ float relL[64][3];
  __shared__ float ppart[4][64];   // reused as qpart
  __shared__ float eijL[64];

  const int tid = threadIdx.x;
  const int e0 = blockIdx.x * 64;
  const int lane = tid & 63, w = tid >> 6;
  const int lr = lane & 15, lg = lane >> 4;
  const int l7 = lr & 7, l3 = lr & 3;
  const int colb = w*32 + lr;      // weight-frag col

  // phase 0 (distributed, 4 threads/edge)
  {
    int row = tid >> 2, sub = tid & 3;
    int e = e0 + row;
    int s = src[e], d = dst[e];
    if (sub == 0) { sL[row] = s; dL[row] = d; }
    float rx = x[3*d+0] - x[3*s+0];
    float ry = x[3*d+1] - x[3*s+1];
    float rz = x[3*d+2] - x[3*s+2];
    if (sub == 1) { relL[row][0] = rx; relL[row][1] = ry; relL[row][2] = rz; }
    float r = rx*rx + ry*ry + rz*rz;
    const float step = 100.0f / 19.0f;
    const float co = -0.5f / (step * step);
    float v6[6];
    if (sub == 0) {
      const float4 efv = reinterpret_cast<const float4*>(ef)[e];
      v6[0]=efv.x; v6[1]=efv.y; v6[2]=efv.z; v6[3]=efv.w;
      float t1 = r - step;
      v6[4] = __expf(co * r * r);
      v6[5] = __expf(co * t1 * t1);
    } else {
      #pragma unroll
      for (int q = 0; q < 6; ++q) {
        float g = (float)(sub*6 - 4 + q) * step;
        float t = r - g;
        v6[q] = __expf(co * t * t);
      }
    }
    #pragma unroll
    for (int q = 0; q < 3; ++q) {
      int c = sub*6 + q*2;
      int chunk = (c>>3) ^ (row&7);
      *reinterpret_cast<unsigned int*>(catB + row*576 + (chunk<<4) + ((c&7)<<1)) = pk2h(v6[q*2], v6[q*2+1]);
    }
    if (sub == 3) {
      U8 z;
      #pragma unroll
      for (int j = 0; j < 8; ++j) z.u[j] = 0;
      *reinterpret_cast<short8*>(catB + row*576 + ((32 + (3 ^ (row&3)))<<4)) = z.v;
    }
  }

  // gather h[dst] (chunks 3..18) and h[src] (chunks 19..34)
  #pragma unroll
  for (int it = 0; it < 8; ++it) {
    int i = tid + it*256;
    int row = i >> 5, c = i & 31;
    int node = (c < 16) ? dst[e0+row] : src[e0+row];
    int chunk = 3 + c;
    int sw = (chunk < 32) ? (chunk ^ (row&7)) : (32 + ((chunk&3) ^ (row&3)));
    if (MODE == 2) {
      short8 u = *reinterpret_cast<const short8*>(hB + (size_t)node*128 + (c&15)*8);
      *reinterpret_cast<short8*>(catB + row*576 + (sw<<4)) = u;
    } else {
      const float4* hp = reinterpret_cast<const float4*>(h + (size_t)node*128 + (c&15)*8);
      float4 a = hp[0], b = hp[1];
      uint4 u;
      u.x = pk2(a.x, a.y); u.y = pk2(a.z, a.w);
      u.z = pk2(b.x, b.y); u.w = pk2(b.z, b.w);
      *reinterpret_cast<uint4*>(catB + row*576 + (sw<<4)) = u;
    }
  }

  // prefetch GEMM1 weight fragments for kt=0,1
  short8 p00 = W1p[(0*4+lg)*128 + colb], p01 = W1p[(0*4+lg)*128 + colb + 16];
  short8 p10 = W1p[(1*4+lg)*128 + colb], p11 = W1p[(1*4+lg)*128 + colb + 16];
  __syncthreads();

  // ---- GEMM1: y1 = relu(cat @ W1 + eb1), K=288 (swapped: D[wcol][edge]) ----
  f32x4 acc[4][2];
  #pragma unroll
  for (int t = 0; t < 4; ++t) { acc[t][0] = (f32x4)0.0f; acc[t][1] = (f32x4)0.0f; }
  #pragma unroll
  for (int kt = 0; kt < 9; ++kt) {
    int ch = (kt < 8) ? ((kt*4+lg) ^ l7) : (32 + (lg ^ l3));
    short8 a0 = *reinterpret_cast<const short8*>(catB + (0*16+lr)*576 + (ch<<4));
    short8 a1 = *reinterpret_cast<const short8*>(catB + (1*16+lr)*576 + (ch<<4));
    short8 a2 = *reinterpret_cast<const short8*>(catB + (2*16+lr)*576 + (ch<<4));
    short8 a3 = *reinterpret_cast<const short8*>(catB + (3*16+lr)*576 + (ch<<4));
    short8 b0, b1;
    if (kt == 0)      { b0 = p00; b1 = p01; }
    else if (kt == 1) { b0 = p10; b1 = p11; }
    else              { b0 = W1p[(kt*4+lg)*128 + colb]; b1 = W1p[(kt*4+lg)*128 + colb + 16]; }
    acc[0][0] = __builtin_amdgcn_mfma_f32_16x16x32_bf16(b0, a0, acc[0][0], 0, 0, 0);
    acc[0][1] = __builtin_amdgcn_mfma_f32_16x16x32_bf16(b1, a0, acc[0][1], 0, 0, 0);
    acc[1][0] = __builtin_amdgcn_mfma_f32_16x16x32_bf16(b0, a1, acc[1][0], 0, 0, 0);
    acc[1][1] = __builtin_amdgcn_mfma_f32_16x16x32_bf16(b1, a1, acc[1][1], 0, 0, 0);
    acc[2][0] = __builtin_amdgcn_mfma_f32_16x16x32_bf16(b0, a2, acc[2][0], 0, 0, 0);
    acc[2][1] = __builtin_amdgcn_mfma_f32_16x16x32_bf16(b1, a2, acc[2][1], 0, 0, 0);
    acc[3][0] = __builtin_amdgcn_mfma_f32_16x16x32_bf16(b0, a3, acc[3][0], 0, 0, 0);
    acc[3][1] = __builtin_amdgcn_mfma_f32_16x16x32_bf16(b1, a3, acc[3][1], 0, 0, 0);
  }
  __syncthreads();  // all cat reads complete before y1 overwrites zone A

  // y1 epilogue: lane holds edge t*16+lr, cols c0j = w*32+j*16+lg*4+{0..3}
  {
    const int c00 = w*32 + lg*4, c01 = c00 + 16;
    float4 be0 = *reinterpret_cast<const float4*>(eb1 + c00);
    float4 be1 = *reinterpret_cast<const float4*>(eb1 + c01);
    #pragma unroll
    for (int t = 0; t < 4; ++t) {
      int row = t*16 + lr;
      char* rowB = catB + row*576;
      #pragma unroll
      for (int j = 0; j < 2; ++j) {
        const float4 be = j ? be1 : be0;
        int c0 = j ? c01 : c00;
        float v0 = fmaxf(acc[t][j][0] + be.x, 0.f);
        float v1 = fmaxf(acc[t][j][1] + be.y, 0.f);
        float v2 = fmaxf(acc[t][j][2] + be.z, 0.f);
        float v3 = fmaxf(acc[t][j][3] + be.w, 0.f);
        uint2 pv; pv.x = pk2h(v0, v1); pv.y = pk2h(v2, v3);
        int chunk = (c0>>3) ^ (row&7);
        *reinterpret_cast<uint2*>(rowB + (chunk<<4) + ((c0&7)<<1)) = pv;
      }
    }
  }
  __syncthreads();  // y1 visible to all waves

  // ---- GEMM2: mij = relu(y1 @ W2 + eb2), K=128 ----
  f32x4 acc2[4][2];
  #pragma unroll
  for (int t = 0; t < 4; ++t) { acc2[t][0] = (f32x4)0.0f; acc2[t][1] = (f32x4)0.0f; }
  #pragma unroll
  for (int kt = 0; kt < 4; ++kt) {
    int ch = (kt*4+lg) ^ l7;
    short8 a0 = *reinterpret_cast<const short8*>(catB + (0*16+lr)*576 + (ch<<4));
    short8 a1 = *reinterpret_cast<const short8*>(catB + (1*16+lr)*576 + (ch<<4));
    short8 a2 = *reinterpret_cast<const short8*>(catB + (2*16+lr)*576 + (ch<<4));
    short8 a3 = *reinterpret_cast<const short8*>(catB + (3*16+lr)*576 + (ch<<4));
    short8 b0 = W2p[(kt*4+lg)*128 + colb];
    short8 b1 = W2p[(kt*4+lg)*128 + colb + 16];
    acc2[0][0] = __builtin_amdgcn_mfma_f32_16x16x32_bf16(b0, a0, acc2[0][0], 0, 0, 0);
    acc2[0][1] = __builtin_amdgcn_mfma_f32_16x16x32_bf16(b1, a0, acc2[0][1], 0, 0, 0);
    acc2[1][0] = __builtin_amdgcn_mfma_f32_16x16x32_bf16(b0, a1, acc2[1][0], 0, 0, 0);
    acc2[1][1] = __builtin_amdgcn_mfma_f32_16x16x32_bf16(b1, a1, acc2[1][1], 0, 0, 0);
    acc2[2][0] = __builtin_amdgcn_mfma_f32_16x16x32_bf16(b0, a2, acc2[2][0], 0, 0, 0);
    acc2[2][1] = __builtin_amdgcn_mfma_f32_16x16x32_bf16(b1, a2, acc2[2][1], 0, 0, 0);
    acc2[3][0] = __builtin_amdgcn_mfma_f32_16x16x32_bf16(b0, a3, acc2[3][0], 0, 0, 0);
    acc2[3][1] = __builtin_amdgcn_mfma_f32_16x16x32_bf16(b1, a3, acc2[3][1], 0, 0, 0);
  }
  // epilogue: mval kept in acc2; mij -> chunks 16..31; per-edge inf partials
  float pl[4];
  {
    const int c00 = w*32 + lg*4, c01 = c00 + 16;
    float4 be0 = *reinterpret_cast<const float4*>(eb2 + c00);
    float4 be1 = *reinterpret_cast<const float4*>(eb2 + c01);
    float4 iw0 = *reinterpret_cast<const float4*>(infw + c00);
    float4 iw1 = *reinterpret_cast<const float4*>(infw + c01);
    #pragma unroll
    for (int t = 0; t < 4; ++t) {
      int row = t*16 + lr;
      char* rowB = catB + row*576;
      pl[t] = 0.f;
      #pragma unroll
      for (int j = 0; j < 2; ++j) {
        const float4 be = j ? be1 : be0;
        const float4 iw = j ? iw1 : iw0;
        int c0 = j ? c01 : c00;
        float v0 = fmaxf(acc2[t][j][0] + be.x, 0.f);
        float v1 = fmaxf(acc2[t][j][1] + be.y, 0.f);
        float v2 = fmaxf(acc2[t][j][2] + be.z, 0.f);
        float v3 = fmaxf(acc2[t][j][3] + be.w, 0.f);
        acc2[t][j][0] = v0; acc2[t][j][1] = v1; acc2[t][j][2] = v2; acc2[t][j][3] = v3;
        pl[t] += v0*iw.x + v1*iw.y + v2*iw.z + v3*iw.w;
        uint2 pv; pv.x = pk2h(v0, v1); pv.y = pk2h(v2, v3);
        int chunk = 16 + ((c0>>3) ^ (row&7));
        *reinterpret_cast<uint2*>(rowB + (chunk<<4) + ((c0&7)<<1)) = pv;
      }
    }
    #pragma unroll
    for (int t = 0; t < 4; ++t) {
      pl[t] += __shfl_xor(pl[t], 16, 64);
      pl[t] += __shfl_xor(pl[t], 32, 64);
    }
    if (lane < 16) {
      #pragma unroll
      for (int t = 0; t < 4; ++t) ppart[w][t*16 + lane] = pl[t];
    }
  }
  __syncthreads();  // sync1: mij + ppart ready

  if (lane < 16) {
    int row2 = w*16 + lane;
    float s2 = ppart[0][row2] + ppart[1][row2] + ppart[2][row2] + ppart[3][row2] + infb[0];
    eijL[row2] = 1.f / (1.f + __expf(-s2));
  }
  __syncthreads();  // sync2: eijL ready

  // ---- stage u = mij*eij into dead y1 zone (chunks 0..15, stage_chunk swizzle) ----
  if (MODE >= 1) {
    const int c00 = w*32 + lg*4, c01 = c00 + 16;
    #pragma unroll
    for (int t = 0; t < 4; ++t) {
      int row = t*16 + lr;
      float e = eijL[row];
      char* rowB = catB + row*576;
      #pragma unroll
      for (int j = 0; j < 2; ++j) {
        int c0 = j ? c01 : c00;
        uint2 pv;
        pv.x = pk2h(acc2[t][j][0]*e, acc2[t][j][1]*e);
        pv.y = pk2h(acc2[t][j][2]*e, acc2[t][j][3]*e);
        *reinterpret_cast<uint2*>(rowB + (stage_chunk(c0, row)<<4) + ((c0&7)<<1)) = pv;
      }
    }
  } else {
    const int c00 = w*32 + lg*4, c01 = c00 + 16;
    #pragma unroll
    for (int t = 0; t < 4; ++t) {
      int row = t*16 + lr;
      int d = dL[row];
      float e = eijL[row];
      float* fp = miF + (size_t)d*128;
      #pragma unroll
      for (int j = 0; j < 2; ++j) {
        int c0 = j ? c01 : c00;
        #pragma unroll
        for (int rg = 0; rg < 4; ++rg) atomicAdd(fp + c0 + rg, acc2[t][j][rg]*e);
      }
    }
  }
  __syncthreads();  // sync2b: u staged

  // ---- coalesced scatter FIRST (GEMM3 below hides the atomic latency) ----
  // per wave instr: 4 dst rows (lg) x 16 consecutive dwords (lr)
  if (MODE >= 1) {
    #pragma unroll
    for (int t = 0; t < 4; ++t)
      #pragma unroll
      for (int rg = 0; rg < 4; ++rg) {
        int row = t*16 + lg*4 + rg;
        int d = dL[row];
        int col0 = w*32 + lr*2;
        unsigned int val = *reinterpret_cast<const unsigned int*>(
            catB + row*576 + (stage_chunk(col0, row)<<4) + ((col0&7)<<1));
        if (val) atomicPkAddBf16(miB + (size_t)d*128 + col0, val);
      }
  }

  // ---- GEMM3: y2 = relu(mij @ XW1 + xb1); x_scale = y2 . xw2 + xb2 ----
  f32x4 acc3[4][2];
  #pragma unroll
  for (int t = 0; t < 4; ++t) { acc3[t][0] = (f32x4)0.0f; acc3[t][1] = (f32x4)0.0f; }
  #pragma unroll
  for (int kt = 0; kt < 4; ++kt) {
    int ch = 16 + ((kt*4+lg) ^ l7);
    short8 a0 = *reinterpret_cast<const short8*>(catB + (0*16+lr)*576 + (ch<<4));
    short8 a1 = *reinterpret_cast<const short8*>(catB + (1*16+lr)*576 + (ch<<4));
    short8 a2 = *reinterpret_cast<const short8*>(catB + (2*16+lr)*576 + (ch<<4));
    short8 a3 = *reinterpret_cast<const short8*>(catB + (3*16+lr)*576 + (ch<<4));
    short8 b0 = XW1p[(kt*4+lg)*128 + colb];
    short8 b1 = XW1p[(kt*4+lg)*128 + colb + 16];
    acc3[0][0] = __builtin_amdgcn_mfma_f32_16x16x32_bf16(b0, a0, acc3[0][0], 0, 0, 0);
    acc3[0][1] = __builtin_amdgcn_mfma_f32_16x16x32_bf16(b1, a0, acc3[0][1], 0, 0, 0);
    acc3[1][0] = __builtin_amdgcn_mfma_f32_16x16x32_bf16(b0, a1, acc3[1][0], 0, 0, 0);
    acc3[1][1] = __builtin_amdgcn_mfma_f32_16x16x32_bf16(b1, a1, acc3[1][1], 0, 0, 0);
    acc3[2][0] = __builtin_amdgcn_mfma_f32_16x16x32_bf16(b0, a2, acc3[2][0], 0, 0, 0);
    acc3[2][1] = __builtin_amdgcn_mfma_f32_16x16x32_bf16(b1, a2, acc3[2][1], 0, 0, 0);
    acc3[3][0] = __builtin_amdgcn_mfma_f32_16x16x32_bf16(b0, a3, acc3[3][0], 0, 0, 0);
    acc3[3][1] = __builtin_amdgcn_mfma_f32_16x16x32_bf16(b1, a3, acc3[3][1], 0, 0, 0);
  }

  // GEMM3 epilogue: x_scale reduce
  {
    const int c00 = w*32 + lg*4, c01 = c00 + 16;
    float4 bx0 = *reinterpret_cast<const float4*>(xb1 + c00);
    float4 bx1 = *reinterpret_cast<const float4*>(xb1 + c01);
    float4 xw0 = *reinterpret_cast<const float4*>(xw2 + c00);
    float4 xw1v = *reinterpret_cast<const float4*>(xw2 + c01);
    float ql[4];
    #pragma unroll
    for (int t = 0; t < 4; ++t) {
      ql[t] = 0.f;
      #pragma unroll
      for (int j = 0; j < 2; ++j) {
        const float4 bx = j ? bx1 : bx0;
        const float4 xw = j ? xw1v : xw0;
        ql[t] += fmaxf(acc3[t][j][0] + bx.x, 0.f) * xw.x
               + fmaxf(acc3[t][j][1] + bx.y, 0.f) * xw.y
               + fmaxf(acc3[t][j][2] + bx.z, 0.f) * xw.z
               + fmaxf(acc3[t][j][3] + bx.w, 0.f) * xw.w;
      }
      ql[t] += __shfl_xor(ql[t], 16, 64);
      ql[t] += __shfl_xor(ql[t], 32, 64);
    }
    if (lane < 16) {
      #pragma unroll
      for (int t = 0; t < 4; ++t) ppart[w][t*16 + lane] = ql[t];
    }
  }
  __syncthreads();  // sync3: qpart ready

  if (tid < 192) {
    int row = tid / 3, c = tid - row*3;
    float q = ppart[0][row] + ppart[1][row] + ppart[2][row] + ppart[3][row] + xb2[0];
    atomicAdd(dx + dL[row]*3 + c, relL[row][c] * q);
  }
}

// ---- node kernel: h_new = h + MLP([mi,h]); x_new = x + dx ----
template<int MODE>
__global__ __launch_bounds__(256) void node_kernel(
    const float* __restrict__ h, const float* __restrict__ x,
    const float* __restrict__ nb1, const float* __restrict__ nb2,
    const short8* __restrict__ NW1p, const short8* __restrict__ NW2p,
    const unsigned short* __restrict__ miB,
    const unsigned short* __restrict__ hB,
    float* __restrict__ out) {
  __shared__ __align__(16) char c2B[64 * 512];  // [64][256] bf16, swizzled
  __shared__ __align__(16) char y3B[64 * 256];  // [64][128] bf16, swizzled
  const int tid = threadIdx.x;
  const int n0 = blockIdx.x * 64;
  const float* mi = out;

  for (int i = tid; i < 64*32; i += 256) {
    int row = i >> 5, c = i & 31;
    int node = n0 + row;
    U8 u;
    if (node < NNODES) {
      if (c < 16 && MODE >= 1) {
        u.v = *reinterpret_cast<const short8*>(miB + (size_t)node*128 + c*8);
      } else if (c >= 16 && MODE == 2) {
        u.v = *reinterpret_cast<const short8*>(hB + (size_t)node*128 + (c-16)*8);
      } else {
        const float4* p = (c < 16)
          ? reinterpret_cast<const float4*>(mi + (size_t)node*128 + c*8)
          : reinterpret_cast<const float4*>(h + (size_t)node*128 + (c-16)*8);
        float4 a = p[0], b = p[1];
        uint4 uu;
        uu.x = pk2(a.x, a.y); uu.y = pk2(a.z, a.w);
        uu.z = pk2(b.x, b.y); uu.w = pk2(b.z, b.w);
        u.v = *reinterpret_cast<short8*>(&uu);
      }
    } else {
      #pragma unroll
      for (int j = 0; j < 8; ++j) u.u[j] = 0;
    }
    *reinterpret_cast<short8*>(c2B + row*512 + ((c ^ (row&7))<<4)) = u.v;
  }
  __syncthreads();

  const int lane = tid & 63, wave = tid >> 6;
  const int lr = lane & 15, lg = lane >> 4;
  const int rb = wave * 16;
  const int arow = rb + lr;

  // GEMM n1: y3 = relu([mi,h] @ NW1 + nb1), K=256
  f32x4 acc[8];
  #pragma unroll
  for (int nt = 0; nt < 8; ++nt) acc[nt] = (f32x4)0.0f;
  #pragma unroll
  for (int kt = 0; kt < 8; ++kt) {
    int chunk = kt*4 + lg;
    short8 a = *reinterpret_cast<const short8*>(c2B + arow*512 + ((chunk ^ (arow&7))<<4));
    const short8* bp = NW1p + chunk*128 + lr;
    #pragma unroll
    for (int nt = 0; nt < 8; ++nt)
      acc[nt] = __builtin_amdgcn_mfma_f32_16x16x32_bf16(a, bp[nt*16], acc[nt], 0, 0, 0);
  }
  #pragma unroll
  for (int nt = 0; nt < 8; ++nt) {
    int col = nt*16 + lr;
    float bias = nb1[col];
    #pragma unroll
    for (int r = 0; r < 4; ++r) {
      int row = rb + lg*4 + r;
      float v = fmaxf(acc[nt][r] + bias, 0.f);
      *reinterpret_cast<unsigned short*>(y3B + row*256 + (((col>>3) ^ (row&7))<<4) + ((col&7)<<1)) = f2b(v);
    }
  }

  // GEMM n2: out = y3 @ NW2 + nb2 + h, K=128
  f32x4 acc2[8];
  #pragma unroll
  for (int nt = 0; nt < 8; ++nt) acc2[nt] = (f32x4)0.0f;
  #pragma unroll
  for (int kt = 0; kt < 4; ++kt) {
    int chunk = kt*4 + lg;
    short8 a = *reinterpret_cast<const short8*>(y3B + arow*256 + ((chunk ^ (arow&7))<<4));
    const short8* bp = NW2p + chunk*128 + lr;
    #pragma unroll
    for (int nt = 0; nt < 8; ++nt)
      acc2[nt] = __builtin_amdgcn_mfma_f32_16x16x32_bf16(a, bp[nt*16], acc2[nt], 0, 0, 0);
  }
  __syncthreads();  // ensure all mi reads (MODE=0 path reads out) done before overwrite
  #pragma unroll
  for (int nt = 0; nt < 8; ++nt) {
    int col = nt*16 + lr;
    float b2 = nb2[col];
    #pragma unroll
    for (int r = 0; r < 4; ++r) {
      int row = rb + lg*4 + r;
      int node = n0 + row;
      if (node < NNODES) {
        int idx = node*128 + col;
        out[idx] = acc2[nt][r] + b2 + h[idx];
      }
    }
  }

  if (tid < 192) {
    int node = n0 + tid/3;
    if (node < NNODES) {
      int idx = node*3 + (tid%3);
      float* xo = out + NNODES*HID;
      xo[idx] = x[idx] + xo[idx];
    }
  }
}

extern "C" void kernel_launch(void* const* d_in, const int* in_sizes, int n_in,
                              void* d_out, int out_size, void* d_ws, size_t ws_size,
                              hipStream_t stream) {
  const int*   src  = (const int*)  d_in[0];
  const int*   dst  = (const int*)  d_in[1];
  const float* ef   = (const float*)d_in[2];
  const float* h    = (const float*)d_in[3];
  const float* x    = (const float*)d_in[4];
  const float* ew1  = (const float*)d_in[5];
  const float* eb1  = (const float*)d_in[6];
  const float* ew2  = (const float*)d_in[7];
  const float* eb2  = (const float*)d_in[8];
  const float* infw = (const float*)d_in[9];
  const float* infb = (const float*)d_in[10];
  const float* xw1  = (const float*)d_in[11];
  const float* xb1  = (const float*)d_in[12];
  const float* xw2  = (const float*)d_in[13];
  const float* xb2  = (const float*)d_in[14];
  const float* nw1  = (const float*)d_in[15];
  const float* nb1  = (const float*)d_in[16];
  const float* nw2  = (const float*)d_in[17];
  const float* nb2  = (const float*)d_in[18];

  float* out = (float*)d_out;
  float* miF = out;                  // f32 fallback
  float* dxp = out + NNODES*HID;
  unsigned short* wsp = (unsigned short*)d_ws;
  unsigned short* miB = wsp + 118784;
  unsigned short* hBp = miB + (size_t)NNODES*HID;

  const size_t MIN = (size_t)NNODES*HID;
  size_t need1 = (118784u + MIN) * 2u;
  size_t need2 = (118784u + 2u*MIN) * 2u;
  int mode = (ws_size >= need2) ? 2 : (ws_size >= need1 ? 1 : 0);

  if (mode >= 1) {
    hipMemsetAsync(miB, 0, MIN*2, stream);
    hipMemsetAsync(dxp, 0, (size_t)NNODES*3*4, stream);
  } else {
    hipMemsetAsync(d_out, 0, (size_t)out_size * sizeof(float), stream);
  }

  pack_kernel<<<464, 256, 0, stream>>>(ew1, ew2, xw1, nw1, nw2, wsp);
  if (mode == 2) hpack_kernel<<<(NNODES*HID)/(256*8), 256, 0, stream>>>(h, hBp);

  if (mode == 2) {
    edge_kernel<2><<<NEDGES/64, 256, 0, stream>>>(
        src, dst, ef, h, x, eb1, eb2, infw, infb, xb1, xw2, xb2,
        (const short8*)wsp, (const short8*)(wsp + 36864), (const short8*)(wsp + 53248),
        hBp, miF, miB, dxp);
    node_kernel<2><<<(NNODES + 63)/64, 256, 0, stream>>>(
        h, x, nb1, nb2,
        (const short8*)(wsp + 69632), (const short8*)(wsp + 102400), miB, hBp, out);
  } else if (mode == 1) {
    edge_kernel<1><<<NEDGES/64, 256, 0, stream>>>(
        src, dst, ef, h, x, eb1, eb2, infw, infb, xb1, xw2, xb2,
        (const short8*)wsp, (const short8*)(wsp + 36864), (const short8*)(wsp + 53248),
        hBp, miF, miB, dxp);
    node_kernel<1><<<(NNODES + 63)/64, 256, 0, stream>>>(
        h, x, nb1, nb2,
        (const short8*)(wsp + 69632), (const short8*)(wsp + 102400), miB, hBp, out);
  } else {
    edge_kernel<0><<<NEDGES/64, 256, 0, stream>>>(
        src, dst, ef, h, x, eb1, eb2, infw, infb, xb1, xw2, xb2,
        (const short8*)wsp, (const short8*)(wsp + 36864), (const short8*)(wsp + 53248),
        hBp, miF, miB, dxp);
    node_kernel<0><<<(NNODES + 63)/64, 256, 0, stream>>>(
        h, x, nb1, nb2,
        (const short8*)(wsp + 69632), (const short8*)(wsp + 102400), miB, hBp, out);
  }
}